// Round 5
// baseline (673.862 us; speedup 1.0000x reference)
//
#include <hip/hip_runtime.h>
#include <hip/hip_bf16.h>

#define NN 100000
#define NNP 100032        // padded node count for xwb tail-block stores
#define NE 1250000
#define DD 64
#define RR 16
#define NTILE 6250        // NN/16 dst-tiles (fallback path)
#define NBINS 100000      // dense: dst; fallback: (dst>>4)*16+rel — same count
#define NBLK_SCAN 391     // ceil(NBINS/256)
#define CAPROWS 224       // fallback staging rows
#define DLCAP 576         // fallback dst-local bytes

typedef __attribute__((ext_vector_type(8))) short s16x8;
typedef __attribute__((ext_vector_type(4))) float f32x4;

static __device__ __forceinline__ unsigned short f2bf(float v) {
    __hip_bfloat16 h = __float2bfloat16(v);
    return __builtin_bit_cast(unsigned short, h);
}
static __device__ __forceinline__ unsigned int pack2(float a, float b) {
    return ((unsigned int)f2bf(b) << 16) | (unsigned int)f2bf(a);
}
static __device__ __forceinline__ float bf2f(unsigned short u) {
    unsigned int x = ((unsigned int)u) << 16;
    return __builtin_bit_cast(float, x);
}

// ---------------- counting sort scaffolding (shared scan; two key variants) ----------------

// dense path: key = dst node
__global__ void hist_dst(const int* __restrict__ dst, int* __restrict__ cnt) {
    int e = blockIdx.x * 256 + threadIdx.x;
    if (e < NE) atomicAdd(&cnt[dst[e]], 1);
}

// ep[p] = src | et<<20
__global__ void scatter_dst(const int* __restrict__ src, const int* __restrict__ dst,
                            const int* __restrict__ et, int* __restrict__ cur,
                            unsigned int* __restrict__ ep) {
    int e = blockIdx.x * 256 + threadIdx.x;
    if (e >= NE) return;
    int p = atomicAdd(&cur[dst[e]], 1);
    ep[p] = (unsigned int)src[e] | ((unsigned int)et[e] << 20);
}

// fallback path: key = (dst>>4)*16 + rel
__global__ void hist_key(const int* __restrict__ dst, const int* __restrict__ et,
                         int* __restrict__ cnt) {
    int e = blockIdx.x * 256 + threadIdx.x;
    if (e < NE) atomicAdd(&cnt[(dst[e] >> 4) * 16 + et[e]], 1);
}

__global__ void scatter_key(const int* __restrict__ src, const int* __restrict__ dst,
                            const int* __restrict__ et, int* __restrict__ cur,
                            unsigned int* __restrict__ ep) {
    int e = blockIdx.x * 256 + threadIdx.x;
    if (e >= NE) return;
    int d = dst[e];
    int p = atomicAdd(&cur[(d >> 4) * 16 + et[e]], 1);
    ep[p] = (unsigned int)src[e] | ((unsigned int)(d & 15) << 20);
}

__global__ __launch_bounds__(256) void scan1(const int* __restrict__ cnt,
                                             int* __restrict__ rp, int* __restrict__ part) {
    __shared__ int s[256];
    int i = blockIdx.x * 256 + threadIdx.x;
    int v = (i < NBINS) ? cnt[i] : 0;
    s[threadIdx.x] = v;
    __syncthreads();
    for (int off = 1; off < 256; off <<= 1) {
        int t = (threadIdx.x >= off) ? s[threadIdx.x - off] : 0;
        __syncthreads();
        s[threadIdx.x] += t;
        __syncthreads();
    }
    if (i < NBINS) rp[i] = s[threadIdx.x] - v;        // exclusive
    if (threadIdx.x == 255) part[blockIdx.x] = s[255];
}

__global__ void scan2(int* __restrict__ part, int* __restrict__ rp) {
    __shared__ int s[NBLK_SCAN];
    if (threadIdx.x < NBLK_SCAN) s[threadIdx.x] = part[threadIdx.x];
    __syncthreads();
    if (threadIdx.x == 0) {
        int acc = 0;
        for (int b = 0; b < NBLK_SCAN; ++b) { int t = s[b]; s[b] = acc; acc += t; }
        rp[NBINS] = NE;
    }
    __syncthreads();
    if (threadIdx.x < NBLK_SCAN) part[threadIdx.x] = s[threadIdx.x];
}

__global__ void scan3(int* __restrict__ rp, const int* __restrict__ part, int* __restrict__ cur) {
    int i = blockIdx.x * 256 + threadIdx.x;
    if (i < NBINS) {
        int v = rp[i] + part[blockIdx.x];
        rp[i] = v;
        cur[i] = v;
    }
}

// ---------------- precision prep ----------------

// wt[l][p][o][d] = bf16( (p<16 ? W_l[p] : sw_l)[d][o] )
__global__ void prep_w2(const float* __restrict__ W1, const float* __restrict__ sw1,
                        const float* __restrict__ W2, const float* __restrict__ sw2,
                        unsigned short* __restrict__ wt) {
    int i = blockIdx.x * 256 + threadIdx.x;
    if (i >= 2 * 17 * DD * DD) return;
    int d = i & 63;
    int o = (i >> 6) & 63;
    int p = (i >> 12) % 17;
    int l = i / (17 * DD * DD);
    const float* srcp;
    if (p < 16) srcp = (l ? W2 : W1) + p * DD * DD;
    else        srcp = (l ? sw2 : sw1);
    wt[i] = f2bf(srcp[d * DD + o]);
}

__global__ void prep_x2(const float* __restrict__ x, unsigned short* __restrict__ xb) {
    int i = blockIdx.x * blockDim.x + threadIdx.x;
    if (i < NN * DD) xb[i] = f2bf(x[i]);
}

// ---------------- dense path kernel 1: xwb[p][n][o] = bf16( xin[n,:] @ W_p ) ----------------
// Block = 64 nodes, 4 waves; wave wid owns 16 nodes (n0..n0+15) and walks all 17 planes.
// MFMA: A = W^T fragment (m=och), B = X fragment (n=node); D: lane(c,q) -> node n0+c,
// och = ob*16 + q*4 + v  => one 8B bf16x4 store per (plane, ob). No LDS, no barriers.
__global__ __launch_bounds__(256) void xw_gemm(const unsigned short* __restrict__ xin,
                                               const unsigned short* __restrict__ wt,
                                               unsigned short* __restrict__ xwb) {
    const int tid  = threadIdx.x;
    const int wid  = tid >> 6;
    const int lane = tid & 63;
    const int c = lane & 15;
    const int q = lane >> 4;
    const int n0 = blockIdx.x * 64 + wid * 16;

    // B fragments (X rows for this wave's 16 nodes) — loaded once, reused by 17 planes
    const unsigned short* xr = xin + (size_t)(n0 + c) * DD + q * 8;
    s16x8 b0 = *(const s16x8*)(xr);
    s16x8 b1 = *(const s16x8*)(xr + 32);

    #pragma unroll 2
    for (int p = 0; p < 17; ++p) {
        const unsigned short* wp = wt + (size_t)p * (DD * DD) + q * 8;
        unsigned short* orow = xwb + ((size_t)p * NNP + n0 + c) * DD + q * 4;
        #pragma unroll
        for (int ob = 0; ob < 4; ++ob) {
            const unsigned short* wrow = wp + (size_t)(ob * 16 + c) * DD;
            s16x8 a0 = *(const s16x8*)(wrow);
            s16x8 a1 = *(const s16x8*)(wrow + 32);
            f32x4 acc = {0.f, 0.f, 0.f, 0.f};
            acc = __builtin_amdgcn_mfma_f32_16x16x32_bf16(a0, b0, acc, 0, 0, 0);
            acc = __builtin_amdgcn_mfma_f32_16x16x32_bf16(a1, b1, acc, 0, 0, 0);
            uint2 val;
            val.x = pack2(acc[0], acc[1]);
            val.y = pack2(acc[2], acc[3]);
            *(uint2*)(orow + ob * 16) = val;
        }
    }
}

// ---------------- dense path kernel 2: per-node gather-aggregate ----------------
// One wave per dst node. acc[lane=och] = xwb[16][n] (self) + bias (+ x residual)
//   + sum over in-edges of xwb[et][src]. Each edge row read = one coalesced 128B load;
// 16 independent row loads in flight per window. No LDS, no barriers, VGPR ~32.
__global__ __launch_bounds__(256) void aggregate(
    const unsigned short* __restrict__ xwb,  // [17][NNP][64] bf16
    const int* __restrict__ rp,              // [NN+1] CSR by dst
    const unsigned int* __restrict__ ep,     // [E] src | et<<20
    const float* __restrict__ bias,
    const float* __restrict__ xres,          // fp32 residual or nullptr
    unsigned short* __restrict__ outb,       // bf16 out (layer 1) or nullptr
    float* __restrict__ outf)                // fp32 out (layer 2) or nullptr
{
    const int tid  = threadIdx.x;
    const int wid  = tid >> 6;
    const int lane = tid & 63;
    const int n = blockIdx.x * 4 + wid;
    if (n >= NN) return;

    const int s0 = rp[n];
    const int s1 = rp[n + 1];

    float acc = bf2f(xwb[((size_t)16 * NNP + n) * DD + lane]);   // self transform
    acc += bias[lane];
    if (xres) acc += xres[(size_t)n * DD + lane];

    for (int base = s0; base < s1; base += 16) {
        unsigned wv[16];
        #pragma unroll
        for (int k = 0; k < 16; ++k)
            wv[k] = ep[min(base + k, s1 - 1)];
        const int m = s1 - base;
        #pragma unroll
        for (int k = 0; k < 16; ++k) {
            if (k < m) {
                const unsigned w = wv[k];
                const unsigned short* rb =
                    xwb + ((size_t)(w >> 20) * NNP + (w & 0xFFFFFu)) * DD;
                acc += bf2f(rb[lane]);
            }
        }
    }

    acc = fmaxf(acc, 0.f);
    if (outb) outb[(size_t)n * DD + lane] = f2bf(acc);
    if (outf) outf[(size_t)n * DD + lane] = acc;
}

// ---------------- fallback fused layer (r4, verified 152us/layer) ----------------
__global__ __launch_bounds__(256, 4) void fused_layer(
    const unsigned short* __restrict__ xb,
    const unsigned short* __restrict__ wt,
    const int* __restrict__ rp,
    const unsigned int* __restrict__ ep,
    const float* __restrict__ bias,
    const float* __restrict__ xres,
    unsigned short* __restrict__ outb,
    float* __restrict__ outf)
{
    __shared__ __attribute__((aligned(16))) unsigned char Ash[CAPROWS * 128];
    __shared__ __attribute__((aligned(8)))  unsigned char dlb[DLCAP + 32];

    const int tid  = threadIdx.x;
    const int wid  = tid >> 6;
    const int lane = tid & 63;
    const int c = lane & 15;
    const int q = lane >> 4;
    const int tile = blockIdx.x;
    const int n0 = tile * 16;

    int rpv = 0;
    if (lane < 17) rpv = rp[tile * 16 + lane];
    const int e0  = __shfl(rpv, 0, 64);
    const int cnt = __shfl(rpv, 16, 64) - e0;

    {
        const int lim = cnt < DLCAP ? cnt : DLCAP;
        for (int i = tid; i < lim; i += 256)
            dlb[i] = (unsigned char)(ep[e0 + i] >> 20);
        if (tid < 32) {
            int p = lim + tid;
            if (p < DLCAP + 32) dlb[p] = 0xFF;
        }
    }
    {
        const int nrows = cnt < CAPROWS ? cnt : CAPROWS;
        const int half = tid & 1;
        for (int i = tid >> 1; i < nrows; i += 128) {
            int src = (int)(ep[e0 + i] & 0xFFFFF);
            const unsigned short* xr = xb + (size_t)src * DD + half * 32;
            s16x8 v0 = *(const s16x8*)(xr);
            s16x8 v1 = *(const s16x8*)(xr + 8);
            s16x8 v2 = *(const s16x8*)(xr + 16);
            s16x8 v3 = *(const s16x8*)(xr + 24);
            unsigned char* bp = Ash + i * 128;
            const int h8 = (i & 7);
            *(s16x8*)(bp + (((half * 4 + 0) ^ h8) * 16)) = v0;
            *(s16x8*)(bp + (((half * 4 + 1) ^ h8) * 16)) = v1;
            *(s16x8*)(bp + (((half * 4 + 2) ^ h8) * 16)) = v2;
            *(s16x8*)(bp + (((half * 4 + 3) ^ h8) * 16)) = v3;
        }
    }
    __syncthreads();

    const bool dlOK = (cnt <= DLCAP);
    const int och = wid * 16 + c;
    const unsigned short* wbase = wt + (size_t)och * DD + q * 8;
    const short one = (short)0x3F80;

    auto plane_body = [&](int r, s16x8 W0, s16x8 W1, f32x4& Dst) {
        const int s0 = __shfl(rpv, r, 64);
        const int s1 = __shfl(rpv, r + 1, 64);
        for (int b0 = s0; b0 < s1; b0 += 16) {
            const int rem = s1 - b0;
            const int lbase = b0 - e0;
            unsigned da;
            if (dlOK) {
                const unsigned* dl32 = (const unsigned*)dlb;
                int idx = lbase + q * 4;
                int w = idx >> 2;
                int sh = (idx & 3) * 8;
                unsigned long long pa =
                    ((unsigned long long)dl32[w + 1] << 32) | dl32[w];
                da = (unsigned)(pa >> sh);
            } else {
                int eA = min(b0 + c, s1 - 1);
                unsigned wa = ep[eA];
                int dl = (b0 + c < s1) ? (int)(wa >> 20) : 31;
                unsigned x0 = (unsigned)__shfl(dl, q * 4 + 0, 64) & 255u;
                unsigned x1 = (unsigned)__shfl(dl, q * 4 + 1, 64) & 255u;
                unsigned x2 = (unsigned)__shfl(dl, q * 4 + 2, 64) & 255u;
                unsigned x3 = (unsigned)__shfl(dl, q * 4 + 3, 64) & 255u;
                da = x0 | (x1 << 8) | (x2 << 16) | (x3 << 24);
            }
            s16x8 a2;
            #pragma unroll
            for (int j = 0; j < 4; ++j) {
                int jj = q * 4 + j;
                a2[j] = ((int)((da >> (8 * j)) & 255) == c && jj < rem) ? one : (short)0;
                a2[j + 4] = 0;
            }
            int rA = min(b0 + c, s1 - 1) - e0;
            s16x8 a0, a1;
            if (rA < CAPROWS) {
                const unsigned char* ap = Ash + rA * 128;
                const int off = (q ^ (rA & 7)) * 16;
                a0 = *(const s16x8*)(ap + off);
                a1 = *(const s16x8*)(ap + (off ^ 64));
            } else {
                int src = (int)(ep[e0 + rA] & 0xFFFFF);
                const unsigned short* xr = xb + (size_t)src * DD + q * 8;
                a0 = *(const s16x8*)(xr);
                a1 = *(const s16x8*)(xr + 32);
            }
            f32x4 cA = {0.f, 0.f, 0.f, 0.f};
            cA = __builtin_amdgcn_mfma_f32_16x16x32_bf16(a0, W0, cA, 0, 0, 0);
            cA = __builtin_amdgcn_mfma_f32_16x16x32_bf16(a1, W1, cA, 0, 0, 0);
            s16x8 bv;
            #pragma unroll
            for (int j = 0; j < 4; ++j) {
                bv[j]     = (short)f2bf(cA[j]);
                bv[j + 4] = 0;
            }
            Dst = __builtin_amdgcn_mfma_f32_16x16x32_bf16(a2, bv, Dst, 0, 0, 0);
        }
    };

    s16x8 wc0 = *(const s16x8*)(wbase);
    s16x8 wc1 = *(const s16x8*)(wbase + 32);
    f32x4 D0 = {0.f, 0.f, 0.f, 0.f};
    f32x4 D1 = {0.f, 0.f, 0.f, 0.f};

    for (int rr = 0; rr < 8; ++rr) {
        const int r = rr * 2;
        const unsigned short* p1 = wbase + (size_t)(r + 1) * (DD * DD);
        s16x8 wn0 = *(const s16x8*)(p1);
        s16x8 wn1 = *(const s16x8*)(p1 + 32);
        plane_body(r, wc0, wc1, D0);
        const int r2 = (r + 2 <= 16) ? r + 2 : 16;
        const unsigned short* p2 = wbase + (size_t)r2 * (DD * DD);
        s16x8 t0 = *(const s16x8*)(p2);
        s16x8 t1 = *(const s16x8*)(p2 + 32);
        plane_body(r + 1, wn0, wn1, D1);
        wc0 = t0; wc1 = t1;
    }
    {
        const unsigned short* xr = xb + (size_t)(n0 + c) * DD + q * 8;
        s16x8 a0 = *(const s16x8*)(xr);
        s16x8 a1 = *(const s16x8*)(xr + 32);
        D0 = __builtin_amdgcn_mfma_f32_16x16x32_bf16(a0, wc0, D0, 0, 0, 0);
        D1 = __builtin_amdgcn_mfma_f32_16x16x32_bf16(a1, wc1, D1, 0, 0, 0);
    }
    f32x4 Dacc = D0 + D1;

    const float bc = bias[och];
    #pragma unroll
    for (int v = 0; v < 4; ++v) {
        const int node = n0 + q * 4 + v;
        float val = Dacc[v] + bc;
        if (xres) val += xres[(size_t)node * DD + och];
        val = fmaxf(val, 0.f);
        if (outf) outf[(size_t)node * DD + och] = val;
        if (outb) {
            float nb = __shfl_xor(val, 1, 64);
            if (!(c & 1))
                *(unsigned int*)(outb + (size_t)node * DD + och) = pack2(val, nb);
        }
    }
}

// ================= launch =================

extern "C" void kernel_launch(void* const* d_in, const int* in_sizes, int n_in,
                              void* d_out, int out_size, void* d_ws, size_t ws_size,
                              hipStream_t stream)
{
    (void)in_sizes; (void)n_in; (void)out_size;
    const float* x    = (const float*)d_in[0];
    const int*   ei   = (const int*)d_in[1];
    const int*   et   = (const int*)d_in[2];
    const float* W1   = (const float*)d_in[3];
    const float* sw1  = (const float*)d_in[4];
    const float* b1   = (const float*)d_in[5];
    const float* W2   = (const float*)d_in[6];
    const float* sw2  = (const float*)d_in[7];
    const float* b2   = (const float*)d_in[8];
    float* out = (float*)d_out;

    const int* srcA = ei;
    const int* dstA = ei + NE;

    char* ws = (char*)d_ws;
    unsigned short* xb   = (unsigned short*)(ws);                 // 12,800,000
    unsigned short* h1b  = (unsigned short*)(ws + 12800000);      // 12,800,000
    unsigned short* wt2  = (unsigned short*)(ws + 25600000);      //    278,528
    unsigned int*   ep   = (unsigned int*)(ws + 25878528);        //  5,000,000
    int*            rp   = (int*)(ws + 30878528);                 //    400,004
    int*            cnt  = (int*)(ws + 31278544);                 //    400,000
    int*            cur  = (int*)(ws + 31678544);                 //    400,000
    int*            part = (int*)(ws + 32078544);                 //      1,600
    const size_t XWB_OFF = 32080640;                              // 128-aligned
    unsigned short* xwb  = (unsigned short*)(ws + XWB_OFF);       // 217,669,632
    const size_t REQ = XWB_OFF + (size_t)17 * NNP * DD * 2;

    const int NB_E    = (NE + 255) / 256;        // 4883
    const int NB_ELEM = (NN * DD + 255) / 256;   // 25000
    const int WPL = 17 * DD * DD;                // wt2 per-layer stride

    const bool dense = (ws_size >= REQ);

    hipMemsetAsync(cnt, 0, NBINS * sizeof(int), stream);
    if (dense) {
        // CSR by dst
        hist_dst<<<NB_E, 256, 0, stream>>>(dstA, cnt);
        scan1<<<NBLK_SCAN, 256, 0, stream>>>(cnt, rp, part);
        scan2<<<1, 512, 0, stream>>>(part, rp);
        scan3<<<NBLK_SCAN, 256, 0, stream>>>(rp, part, cur);
        scatter_dst<<<NB_E, 256, 0, stream>>>(srcA, dstA, et, cur, ep);
    } else {
        hist_key<<<NB_E, 256, 0, stream>>>(dstA, et, cnt);
        scan1<<<NBLK_SCAN, 256, 0, stream>>>(cnt, rp, part);
        scan2<<<1, 512, 0, stream>>>(part, rp);
        scan3<<<NBLK_SCAN, 256, 0, stream>>>(rp, part, cur);
        scatter_key<<<NB_E, 256, 0, stream>>>(srcA, dstA, et, cur, ep);
    }

    prep_w2<<<(2 * 17 * DD * DD + 255) / 256, 256, 0, stream>>>(W1, sw1, W2, sw2, wt2);
    prep_x2<<<NB_ELEM, 256, 0, stream>>>(x, xb);

    if (dense) {
        const int NB_G = (NN + 63) / 64;     // 1563
        const int NB_A = (NN + 3) / 4;       // 25000
        // layer 1
        xw_gemm<<<NB_G, 256, 0, stream>>>(xb, wt2, xwb);
        aggregate<<<NB_A, 256, 0, stream>>>(xwb, rp, ep, b1, x, h1b, nullptr);
        // layer 2
        xw_gemm<<<NB_G, 256, 0, stream>>>(h1b, wt2 + WPL, xwb);
        aggregate<<<NB_A, 256, 0, stream>>>(xwb, rp, ep, b2, nullptr, nullptr, out);
    } else {
        fused_layer<<<NTILE, 256, 0, stream>>>(xb, wt2, rp, ep, b1, x, h1b, nullptr);
        fused_layer<<<NTILE, 256, 0, stream>>>(h1b, wt2 + WPL, rp, ep, b2, nullptr, nullptr, out);
    }
}

// Round 6
// 612.405 us; speedup vs baseline: 1.1004x; 1.1004x over previous
//
#include <hip/hip_runtime.h>
#include <hip/hip_bf16.h>

#define NN 100000
#define NNP 100032        // padded node count; 521*192 tiles cover exactly NNP
#define NE 1250000
#define DD 64
#define RR 16
#define NTILE 6250        // fallback path
#define NBINS 100000      // dense: dst; fallback: (dst>>4)*16+rel
#define NBLK_SCAN 391     // ceil(NBINS/256)
#define CAPROWS 224       // fallback staging rows
#define DLCAP 576         // fallback dst-local bytes
#define NB_E_C 4883       // ceil(NE/256)
#define NB_W_C 544        // ceil(2*17*64*64/256)
#define NB_X_C 25000      // NN*DD/256

typedef __attribute__((ext_vector_type(8))) short s16x8;
typedef __attribute__((ext_vector_type(4))) float f32x4;

static __device__ __forceinline__ unsigned short f2bf(float v) {
    __hip_bfloat16 h = __float2bfloat16(v);
    return __builtin_bit_cast(unsigned short, h);
}
static __device__ __forceinline__ unsigned int pack2(float a, float b) {
    return ((unsigned int)f2bf(b) << 16) | (unsigned int)f2bf(a);
}
static __device__ __forceinline__ float bf2f(unsigned short u) {
    unsigned int x = ((unsigned int)u) << 16;
    return __builtin_bit_cast(float, x);
}

// ---------------- merged prologue (dense path): hist_dst + prep_w + prep_x ----------------

__global__ void prologue(const int* __restrict__ dst,
                         const float* __restrict__ W1, const float* __restrict__ sw1,
                         const float* __restrict__ W2, const float* __restrict__ sw2,
                         const float* __restrict__ x,
                         int* __restrict__ cnt, unsigned short* __restrict__ wt,
                         unsigned short* __restrict__ xb) {
    int b = blockIdx.x;
    if (b < NB_E_C) {
        int e = b * 256 + threadIdx.x;
        if (e < NE) atomicAdd(&cnt[dst[e]], 1);
        return;
    }
    b -= NB_E_C;
    if (b < NB_W_C) {
        int i = b * 256 + threadIdx.x;
        if (i < 2 * 17 * DD * DD) {
            int d = i & 63;
            int o = (i >> 6) & 63;
            int p = (i >> 12) % 17;
            int l = i / (17 * DD * DD);
            const float* srcp;
            if (p < 16) srcp = (l ? W2 : W1) + p * DD * DD;
            else        srcp = (l ? sw2 : sw1);
            wt[i] = f2bf(srcp[d * DD + o]);
        }
        return;
    }
    b -= NB_W_C;
    int i = b * 256 + threadIdx.x;
    if (i < NN * DD) xb[i] = f2bf(x[i]);
}

// ep[p] = src | et<<20
__global__ void scatter_dst(const int* __restrict__ src, const int* __restrict__ dst,
                            const int* __restrict__ et, int* __restrict__ cur,
                            unsigned int* __restrict__ ep) {
    int e = blockIdx.x * 256 + threadIdx.x;
    if (e >= NE) return;
    int p = atomicAdd(&cur[dst[e]], 1);
    ep[p] = (unsigned int)src[e] | ((unsigned int)et[e] << 20);
}

// fallback path: key = (dst>>4)*16 + rel
__global__ void hist_key(const int* __restrict__ dst, const int* __restrict__ et,
                         int* __restrict__ cnt) {
    int e = blockIdx.x * 256 + threadIdx.x;
    if (e < NE) atomicAdd(&cnt[(dst[e] >> 4) * 16 + et[e]], 1);
}

__global__ void scatter_key(const int* __restrict__ src, const int* __restrict__ dst,
                            const int* __restrict__ et, int* __restrict__ cur,
                            unsigned int* __restrict__ ep) {
    int e = blockIdx.x * 256 + threadIdx.x;
    if (e >= NE) return;
    int d = dst[e];
    int p = atomicAdd(&cur[(d >> 4) * 16 + et[e]], 1);
    ep[p] = (unsigned int)src[e] | ((unsigned int)(d & 15) << 20);
}

__global__ __launch_bounds__(256) void scan1(const int* __restrict__ cnt,
                                             int* __restrict__ rp, int* __restrict__ part) {
    __shared__ int s[256];
    int i = blockIdx.x * 256 + threadIdx.x;
    int v = (i < NBINS) ? cnt[i] : 0;
    s[threadIdx.x] = v;
    __syncthreads();
    for (int off = 1; off < 256; off <<= 1) {
        int t = (threadIdx.x >= off) ? s[threadIdx.x - off] : 0;
        __syncthreads();
        s[threadIdx.x] += t;
        __syncthreads();
    }
    if (i < NBINS) rp[i] = s[threadIdx.x] - v;        // exclusive
    if (threadIdx.x == 255) part[blockIdx.x] = s[255];
}

__global__ void scan2(int* __restrict__ part, int* __restrict__ rp) {
    __shared__ int s[NBLK_SCAN];
    if (threadIdx.x < NBLK_SCAN) s[threadIdx.x] = part[threadIdx.x];
    __syncthreads();
    if (threadIdx.x == 0) {
        int acc = 0;
        for (int b = 0; b < NBLK_SCAN; ++b) { int t = s[b]; s[b] = acc; acc += t; }
        rp[NBINS] = NE;
    }
    __syncthreads();
    if (threadIdx.x < NBLK_SCAN) part[threadIdx.x] = s[threadIdx.x];
}

__global__ void scan3(int* __restrict__ rp, const int* __restrict__ part, int* __restrict__ cur) {
    int i = blockIdx.x * 256 + threadIdx.x;
    if (i < NBINS) {
        int v = rp[i] + part[blockIdx.x];
        rp[i] = v;
        cur[i] = v;
    }
}

// ---------------- fallback-only prep kernels ----------------

__global__ void prep_w2(const float* __restrict__ W1, const float* __restrict__ sw1,
                        const float* __restrict__ W2, const float* __restrict__ sw2,
                        unsigned short* __restrict__ wt) {
    int i = blockIdx.x * 256 + threadIdx.x;
    if (i >= 2 * 17 * DD * DD) return;
    int d = i & 63;
    int o = (i >> 6) & 63;
    int p = (i >> 12) % 17;
    int l = i / (17 * DD * DD);
    const float* srcp;
    if (p < 16) srcp = (l ? W2 : W1) + p * DD * DD;
    else        srcp = (l ? sw2 : sw1);
    wt[i] = f2bf(srcp[d * DD + o]);
}

__global__ void prep_x2(const float* __restrict__ x, unsigned short* __restrict__ xb) {
    int i = blockIdx.x * blockDim.x + threadIdx.x;
    if (i < NN * DD) xb[i] = f2bf(x[i]);
}

// ---------------- dense kernel 1: xwb[p][n][o] = bf16( xin[n,:] @ W_p ) ----------------
// Grid (17 planes, 521 node-tiles of 192). Block = 4 waves; wave wid = och-block ob.
// Weight fragments loaded ONCE per wave (r5 reloaded them per step with VGPR=20 -> no
// pipelining, 130us at 1.8TB/s). 12 independent chunks per wave: {2 x-row loads, 2 MFMA,
// pack, one 8B store} -> deep MLP, write-roofline-bound.
__global__ __launch_bounds__(256, 6) void xw_gemm(const unsigned short* __restrict__ xin,
                                                  const unsigned short* __restrict__ wt,
                                                  unsigned short* __restrict__ xwb) {
    const int tid  = threadIdx.x;
    const int ob   = tid >> 6;
    const int lane = tid & 63;
    const int c = lane & 15;
    const int q = lane >> 4;
    const int p  = blockIdx.x;            // plane 0..16
    const int n0 = blockIdx.y * 192;      // node tile (521*192 == NNP exactly)

    const unsigned short* wrow = wt + (size_t)p * (DD * DD) + (size_t)(ob * 16 + c) * DD + q * 8;
    s16x8 a0 = *(const s16x8*)(wrow);
    s16x8 a1 = *(const s16x8*)(wrow + 32);

    const unsigned short* xr0 = xin + (size_t)(n0 + c) * DD + q * 8;
    unsigned short* ob0 = xwb + ((size_t)p * NNP + n0 + c) * DD + ob * 16 + q * 4;

    #pragma unroll 4
    for (int t = 0; t < 12; ++t) {
        const unsigned short* xr = xr0 + (size_t)t * 16 * DD;
        s16x8 b0 = *(const s16x8*)(xr);
        s16x8 b1 = *(const s16x8*)(xr + 32);
        f32x4 acc = {0.f, 0.f, 0.f, 0.f};
        acc = __builtin_amdgcn_mfma_f32_16x16x32_bf16(a0, b0, acc, 0, 0, 0);
        acc = __builtin_amdgcn_mfma_f32_16x16x32_bf16(a1, b1, acc, 0, 0, 0);
        uint2 val;
        val.x = pack2(acc[0], acc[1]);
        val.y = pack2(acc[2], acc[3]);
        *(uint2*)(ob0 + (size_t)t * 16 * DD) = val;
    }
}

// ---------------- dense kernel 2: per-node gather-aggregate ----------------
// One wave per dst node. 16 unconditional-address row loads per window (min-clamped),
// predication applied AFTER the load; 4 partial accumulators break the fadd chain.
__global__ __launch_bounds__(256, 8) void aggregate(
    const unsigned short* __restrict__ xwb,  // [17][NNP][64] bf16
    const int* __restrict__ rp,              // [NN+1] CSR by dst
    const unsigned int* __restrict__ ep,     // [E] src | et<<20
    const float* __restrict__ bias,
    const float* __restrict__ xres,          // fp32 residual or nullptr
    unsigned short* __restrict__ outb,       // bf16 out (layer 1) or nullptr
    float* __restrict__ outf)                // fp32 out (layer 2) or nullptr
{
    const int tid  = threadIdx.x;
    const int wid  = tid >> 6;
    const int lane = tid & 63;
    const int n = blockIdx.x * 4 + wid;
    if (n >= NN) return;

    const int s0 = rp[n];
    const int s1 = rp[n + 1];

    float acc0 = bf2f(xwb[((size_t)16 * NNP + n) * DD + lane]);   // self transform
    acc0 += bias[lane];
    if (xres) acc0 += xres[(size_t)n * DD + lane];
    float acc1 = 0.f, acc2 = 0.f, acc3 = 0.f;

    for (int base = s0; base < s1; base += 16) {
        const int m = s1 - base;
        unsigned wv[16];
        #pragma unroll
        for (int k = 0; k < 16; ++k)
            wv[k] = ep[min(base + k, s1 - 1)];
        float vals[16];
        #pragma unroll
        for (int k = 0; k < 16; ++k) {
            const unsigned w = wv[k];
            vals[k] = bf2f(xwb[((size_t)(w >> 20) * NNP + (w & 0xFFFFFu)) * DD + lane]);
        }
        #pragma unroll
        for (int k = 0; k < 16; ++k) {
            float v = (k < m) ? vals[k] : 0.f;
            if ((k & 3) == 0) acc0 += v;
            else if ((k & 3) == 1) acc1 += v;
            else if ((k & 3) == 2) acc2 += v;
            else acc3 += v;
        }
    }

    float acc = (acc0 + acc1) + (acc2 + acc3);
    acc = fmaxf(acc, 0.f);
    if (outb) outb[(size_t)n * DD + lane] = f2bf(acc);
    if (outf) outf[(size_t)n * DD + lane] = acc;
}

// ---------------- fallback fused layer (r4, verified 152us/layer) ----------------
__global__ __launch_bounds__(256, 4) void fused_layer(
    const unsigned short* __restrict__ xb,
    const unsigned short* __restrict__ wt,
    const int* __restrict__ rp,
    const unsigned int* __restrict__ ep,
    const float* __restrict__ bias,
    const float* __restrict__ xres,
    unsigned short* __restrict__ outb,
    float* __restrict__ outf)
{
    __shared__ __attribute__((aligned(16))) unsigned char Ash[CAPROWS * 128];
    __shared__ __attribute__((aligned(8)))  unsigned char dlb[DLCAP + 32];

    const int tid  = threadIdx.x;
    const int wid  = tid >> 6;
    const int lane = tid & 63;
    const int c = lane & 15;
    const int q = lane >> 4;
    const int tile = blockIdx.x;
    const int n0 = tile * 16;

    int rpv = 0;
    if (lane < 17) rpv = rp[tile * 16 + lane];
    const int e0  = __shfl(rpv, 0, 64);
    const int cnt = __shfl(rpv, 16, 64) - e0;

    {
        const int lim = cnt < DLCAP ? cnt : DLCAP;
        for (int i = tid; i < lim; i += 256)
            dlb[i] = (unsigned char)(ep[e0 + i] >> 20);
        if (tid < 32) {
            int p = lim + tid;
            if (p < DLCAP + 32) dlb[p] = 0xFF;
        }
    }
    {
        const int nrows = cnt < CAPROWS ? cnt : CAPROWS;
        const int half = tid & 1;
        for (int i = tid >> 1; i < nrows; i += 128) {
            int src = (int)(ep[e0 + i] & 0xFFFFF);
            const unsigned short* xr = xb + (size_t)src * DD + half * 32;
            s16x8 v0 = *(const s16x8*)(xr);
            s16x8 v1 = *(const s16x8*)(xr + 8);
            s16x8 v2 = *(const s16x8*)(xr + 16);
            s16x8 v3 = *(const s16x8*)(xr + 24);
            unsigned char* bp = Ash + i * 128;
            const int h8 = (i & 7);
            *(s16x8*)(bp + (((half * 4 + 0) ^ h8) * 16)) = v0;
            *(s16x8*)(bp + (((half * 4 + 1) ^ h8) * 16)) = v1;
            *(s16x8*)(bp + (((half * 4 + 2) ^ h8) * 16)) = v2;
            *(s16x8*)(bp + (((half * 4 + 3) ^ h8) * 16)) = v3;
        }
    }
    __syncthreads();

    const bool dlOK = (cnt <= DLCAP);
    const int och = wid * 16 + c;
    const unsigned short* wbase = wt + (size_t)och * DD + q * 8;
    const short one = (short)0x3F80;

    auto plane_body = [&](int r, s16x8 W0, s16x8 W1, f32x4& Dst) {
        const int s0 = __shfl(rpv, r, 64);
        const int s1 = __shfl(rpv, r + 1, 64);
        for (int b0 = s0; b0 < s1; b0 += 16) {
            const int rem = s1 - b0;
            const int lbase = b0 - e0;
            unsigned da;
            if (dlOK) {
                const unsigned* dl32 = (const unsigned*)dlb;
                int idx = lbase + q * 4;
                int w = idx >> 2;
                int sh = (idx & 3) * 8;
                unsigned long long pa =
                    ((unsigned long long)dl32[w + 1] << 32) | dl32[w];
                da = (unsigned)(pa >> sh);
            } else {
                int eA = min(b0 + c, s1 - 1);
                unsigned wa = ep[eA];
                int dl = (b0 + c < s1) ? (int)(wa >> 20) : 31;
                unsigned x0 = (unsigned)__shfl(dl, q * 4 + 0, 64) & 255u;
                unsigned x1 = (unsigned)__shfl(dl, q * 4 + 1, 64) & 255u;
                unsigned x2 = (unsigned)__shfl(dl, q * 4 + 2, 64) & 255u;
                unsigned x3 = (unsigned)__shfl(dl, q * 4 + 3, 64) & 255u;
                da = x0 | (x1 << 8) | (x2 << 16) | (x3 << 24);
            }
            s16x8 a2;
            #pragma unroll
            for (int j = 0; j < 4; ++j) {
                int jj = q * 4 + j;
                a2[j] = ((int)((da >> (8 * j)) & 255) == c && jj < rem) ? one : (short)0;
                a2[j + 4] = 0;
            }
            int rA = min(b0 + c, s1 - 1) - e0;
            s16x8 a0, a1;
            if (rA < CAPROWS) {
                const unsigned char* ap = Ash + rA * 128;
                const int off = (q ^ (rA & 7)) * 16;
                a0 = *(const s16x8*)(ap + off);
                a1 = *(const s16x8*)(ap + (off ^ 64));
            } else {
                int src = (int)(ep[e0 + rA] & 0xFFFFF);
                const unsigned short* xr = xb + (size_t)src * DD + q * 8;
                a0 = *(const s16x8*)(xr);
                a1 = *(const s16x8*)(xr + 32);
            }
            f32x4 cA = {0.f, 0.f, 0.f, 0.f};
            cA = __builtin_amdgcn_mfma_f32_16x16x32_bf16(a0, W0, cA, 0, 0, 0);
            cA = __builtin_amdgcn_mfma_f32_16x16x32_bf16(a1, W1, cA, 0, 0, 0);
            s16x8 bv;
            #pragma unroll
            for (int j = 0; j < 4; ++j) {
                bv[j]     = (short)f2bf(cA[j]);
                bv[j + 4] = 0;
            }
            Dst = __builtin_amdgcn_mfma_f32_16x16x32_bf16(a2, bv, Dst, 0, 0, 0);
        }
    };

    s16x8 wc0 = *(const s16x8*)(wbase);
    s16x8 wc1 = *(const s16x8*)(wbase + 32);
    f32x4 D0 = {0.f, 0.f, 0.f, 0.f};
    f32x4 D1 = {0.f, 0.f, 0.f, 0.f};

    for (int rr = 0; rr < 8; ++rr) {
        const int r = rr * 2;
        const unsigned short* p1 = wbase + (size_t)(r + 1) * (DD * DD);
        s16x8 wn0 = *(const s16x8*)(p1);
        s16x8 wn1 = *(const s16x8*)(p1 + 32);
        plane_body(r, wc0, wc1, D0);
        const int r2 = (r + 2 <= 16) ? r + 2 : 16;
        const unsigned short* p2 = wbase + (size_t)r2 * (DD * DD);
        s16x8 t0 = *(const s16x8*)(p2);
        s16x8 t1 = *(const s16x8*)(p2 + 32);
        plane_body(r + 1, wn0, wn1, D1);
        wc0 = t0; wc1 = t1;
    }
    {
        const unsigned short* xr = xb + (size_t)(n0 + c) * DD + q * 8;
        s16x8 a0 = *(const s16x8*)(xr);
        s16x8 a1 = *(const s16x8*)(xr + 32);
        D0 = __builtin_amdgcn_mfma_f32_16x16x32_bf16(a0, wc0, D0, 0, 0, 0);
        D1 = __builtin_amdgcn_mfma_f32_16x16x32_bf16(a1, wc1, D1, 0, 0, 0);
    }
    f32x4 Dacc = D0 + D1;

    const float bc = bias[och];
    #pragma unroll
    for (int v = 0; v < 4; ++v) {
        const int node = n0 + q * 4 + v;
        float val = Dacc[v] + bc;
        if (xres) val += xres[(size_t)node * DD + och];
        val = fmaxf(val, 0.f);
        if (outf) outf[(size_t)node * DD + och] = val;
        if (outb) {
            float nb = __shfl_xor(val, 1, 64);
            if (!(c & 1))
                *(unsigned int*)(outb + (size_t)node * DD + och) = pack2(val, nb);
        }
    }
}

// ================= launch =================

extern "C" void kernel_launch(void* const* d_in, const int* in_sizes, int n_in,
                              void* d_out, int out_size, void* d_ws, size_t ws_size,
                              hipStream_t stream)
{
    (void)in_sizes; (void)n_in; (void)out_size;
    const float* x    = (const float*)d_in[0];
    const int*   ei   = (const int*)d_in[1];
    const int*   et   = (const int*)d_in[2];
    const float* W1   = (const float*)d_in[3];
    const float* sw1  = (const float*)d_in[4];
    const float* b1   = (const float*)d_in[5];
    const float* W2   = (const float*)d_in[6];
    const float* sw2  = (const float*)d_in[7];
    const float* b2   = (const float*)d_in[8];
    float* out = (float*)d_out;

    const int* srcA = ei;
    const int* dstA = ei + NE;

    char* ws = (char*)d_ws;
    unsigned short* xb   = (unsigned short*)(ws);                 // 12,800,000
    unsigned short* h1b  = (unsigned short*)(ws + 12800000);      // 12,800,000
    unsigned short* wt2  = (unsigned short*)(ws + 25600000);      //    278,528
    unsigned int*   ep   = (unsigned int*)(ws + 25878528);        //  5,000,000
    int*            rp   = (int*)(ws + 30878528);                 //    400,004
    int*            cnt  = (int*)(ws + 31278544);                 //    400,000
    int*            cur  = (int*)(ws + 31678544);                 //    400,000
    int*            part = (int*)(ws + 32078544);                 //      1,600
    const size_t XWB_OFF = 32080640;                              // 128-aligned
    unsigned short* xwb  = (unsigned short*)(ws + XWB_OFF);       // 217,669,632
    const size_t REQ = XWB_OFF + (size_t)17 * NNP * DD * 2;

    const int NB_E    = (NE + 255) / 256;        // 4883
    const int NB_ELEM = (NN * DD + 255) / 256;   // 25000
    const int WPL = 17 * DD * DD;                // wt2 per-layer stride

    const bool dense = (ws_size >= REQ);

    hipMemsetAsync(cnt, 0, NBINS * sizeof(int), stream);
    if (dense) {
        // merged hist_dst + prep_w + prep_x
        prologue<<<NB_E_C + NB_W_C + NB_X_C, 256, 0, stream>>>(
            dstA, W1, sw1, W2, sw2, x, cnt, wt2, xb);
        scan1<<<NBLK_SCAN, 256, 0, stream>>>(cnt, rp, part);
        scan2<<<1, 512, 0, stream>>>(part, rp);
        scan3<<<NBLK_SCAN, 256, 0, stream>>>(rp, part, cur);
        scatter_dst<<<NB_E, 256, 0, stream>>>(srcA, dstA, et, cur, ep);

        const dim3 gG(17, 521);              // 521*192 == NNP
        const int NB_A = (NN + 3) / 4;       // 25000
        // layer 1
        xw_gemm<<<gG, 256, 0, stream>>>(xb, wt2, xwb);
        aggregate<<<NB_A, 256, 0, stream>>>(xwb, rp, ep, b1, x, h1b, nullptr);
        // layer 2
        xw_gemm<<<gG, 256, 0, stream>>>(h1b, wt2 + WPL, xwb);
        aggregate<<<NB_A, 256, 0, stream>>>(xwb, rp, ep, b2, nullptr, nullptr, out);
    } else {
        hist_key<<<NB_E, 256, 0, stream>>>(dstA, et, cnt);
        scan1<<<NBLK_SCAN, 256, 0, stream>>>(cnt, rp, part);
        scan2<<<1, 512, 0, stream>>>(part, rp);
        scan3<<<NBLK_SCAN, 256, 0, stream>>>(rp, part, cur);
        scatter_key<<<NB_E, 256, 0, stream>>>(srcA, dstA, et, cur, ep);
        prep_w2<<<(2 * 17 * DD * DD + 255) / 256, 256, 0, stream>>>(W1, sw1, W2, sw2, wt2);
        prep_x2<<<NB_ELEM, 256, 0, stream>>>(x, xb);
        fused_layer<<<NTILE, 256, 0, stream>>>(xb, wt2, rp, ep, b1, x, h1b, nullptr);
        fused_layer<<<NTILE, 256, 0, stream>>>(h1b, wt2 + WPL, rp, ep, b2, nullptr, nullptr, out);
    }
}

// Round 7
// 498.093 us; speedup vs baseline: 1.3529x; 1.2295x over previous
//
#include <hip/hip_runtime.h>
#include <hip/hip_bf16.h>

#define NN 100000
#define NNP 100096        // padded node count; 782*128 tiles cover exactly NNP
#define NE 1250000
#define DD 64
#define RR 16
#define NTILE 6250        // fallback path
#define NBINS 100000      // dense: dst; fallback: (dst>>4)*16+rel
#define NBLK_SCAN 391     // ceil(NBINS/256)
#define CAPROWS 224       // fallback staging rows
#define DLCAP 576         // fallback dst-local bytes
#define NB_E_C 4883       // ceil(NE/256)
#define NB_W_C 544        // ceil(2*17*64*64/256)
#define NB_X_C 25000      // NN*DD/256

typedef __attribute__((ext_vector_type(8))) short s16x8;
typedef __attribute__((ext_vector_type(4))) float f32x4;

static __device__ __forceinline__ unsigned short f2bf(float v) {
    __hip_bfloat16 h = __float2bfloat16(v);
    return __builtin_bit_cast(unsigned short, h);
}
static __device__ __forceinline__ unsigned int pack2(float a, float b) {
    return ((unsigned int)f2bf(b) << 16) | (unsigned int)f2bf(a);
}
static __device__ __forceinline__ float bf2f(unsigned short u) {
    unsigned int x = ((unsigned int)u) << 16;
    return __builtin_bit_cast(float, x);
}

// ---------------- merged prologue (dense path): hist_dst + prep_w + prep_x ----------------

__global__ void prologue(const int* __restrict__ dst,
                         const float* __restrict__ W1, const float* __restrict__ sw1,
                         const float* __restrict__ W2, const float* __restrict__ sw2,
                         const float* __restrict__ x,
                         int* __restrict__ cnt, unsigned short* __restrict__ wt,
                         unsigned short* __restrict__ xb) {
    int b = blockIdx.x;
    if (b < NB_E_C) {
        int e = b * 256 + threadIdx.x;
        if (e < NE) atomicAdd(&cnt[dst[e]], 1);
        return;
    }
    b -= NB_E_C;
    if (b < NB_W_C) {
        int i = b * 256 + threadIdx.x;
        if (i < 2 * 17 * DD * DD) {
            int d = i & 63;
            int o = (i >> 6) & 63;
            int p = (i >> 12) % 17;
            int l = i / (17 * DD * DD);
            const float* srcp;
            if (p < 16) srcp = (l ? W2 : W1) + p * DD * DD;
            else        srcp = (l ? sw2 : sw1);
            wt[i] = f2bf(srcp[d * DD + o]);
        }
        return;
    }
    b -= NB_W_C;
    int i = b * 256 + threadIdx.x;
    if (i < NN * DD) xb[i] = f2bf(x[i]);
}

// ep[p] = src | et<<20
__global__ void scatter_dst(const int* __restrict__ src, const int* __restrict__ dst,
                            const int* __restrict__ et, int* __restrict__ cur,
                            unsigned int* __restrict__ ep) {
    int e = blockIdx.x * 256 + threadIdx.x;
    if (e >= NE) return;
    int p = atomicAdd(&cur[dst[e]], 1);
    ep[p] = (unsigned int)src[e] | ((unsigned int)et[e] << 20);
}

// fallback path: key = (dst>>4)*16 + rel
__global__ void hist_key(const int* __restrict__ dst, const int* __restrict__ et,
                         int* __restrict__ cnt) {
    int e = blockIdx.x * 256 + threadIdx.x;
    if (e < NE) atomicAdd(&cnt[(dst[e] >> 4) * 16 + et[e]], 1);
}

__global__ void scatter_key(const int* __restrict__ src, const int* __restrict__ dst,
                            const int* __restrict__ et, int* __restrict__ cur,
                            unsigned int* __restrict__ ep) {
    int e = blockIdx.x * 256 + threadIdx.x;
    if (e >= NE) return;
    int d = dst[e];
    int p = atomicAdd(&cur[(d >> 4) * 16 + et[e]], 1);
    ep[p] = (unsigned int)src[e] | ((unsigned int)(d & 15) << 20);
}

__global__ __launch_bounds__(256) void scan1(const int* __restrict__ cnt,
                                             int* __restrict__ rp, int* __restrict__ part) {
    __shared__ int s[256];
    int i = blockIdx.x * 256 + threadIdx.x;
    int v = (i < NBINS) ? cnt[i] : 0;
    s[threadIdx.x] = v;
    __syncthreads();
    for (int off = 1; off < 256; off <<= 1) {
        int t = (threadIdx.x >= off) ? s[threadIdx.x - off] : 0;
        __syncthreads();
        s[threadIdx.x] += t;
        __syncthreads();
    }
    if (i < NBINS) rp[i] = s[threadIdx.x] - v;        // exclusive
    if (threadIdx.x == 255) part[blockIdx.x] = s[255];
}

__global__ void scan2(int* __restrict__ part, int* __restrict__ rp) {
    __shared__ int s[NBLK_SCAN];
    if (threadIdx.x < NBLK_SCAN) s[threadIdx.x] = part[threadIdx.x];
    __syncthreads();
    if (threadIdx.x == 0) {
        int acc = 0;
        for (int b = 0; b < NBLK_SCAN; ++b) { int t = s[b]; s[b] = acc; acc += t; }
        rp[NBINS] = NE;
    }
    __syncthreads();
    if (threadIdx.x < NBLK_SCAN) part[threadIdx.x] = s[threadIdx.x];
}

__global__ void scan3(int* __restrict__ rp, const int* __restrict__ part, int* __restrict__ cur) {
    int i = blockIdx.x * 256 + threadIdx.x;
    if (i < NBINS) {
        int v = rp[i] + part[blockIdx.x];
        rp[i] = v;
        cur[i] = v;
    }
}

// ---------------- fallback-only prep kernels ----------------

__global__ void prep_w2(const float* __restrict__ W1, const float* __restrict__ sw1,
                        const float* __restrict__ W2, const float* __restrict__ sw2,
                        unsigned short* __restrict__ wt) {
    int i = blockIdx.x * 256 + threadIdx.x;
    if (i >= 2 * 17 * DD * DD) return;
    int d = i & 63;
    int o = (i >> 6) & 63;
    int p = (i >> 12) % 17;
    int l = i / (17 * DD * DD);
    const float* srcp;
    if (p < 16) srcp = (l ? W2 : W1) + p * DD * DD;
    else        srcp = (l ? sw2 : sw1);
    wt[i] = f2bf(srcp[d * DD + o]);
}

__global__ void prep_x2(const float* __restrict__ x, unsigned short* __restrict__ xb) {
    int i = blockIdx.x * blockDim.x + threadIdx.x;
    if (i < NN * DD) xb[i] = f2bf(x[i]);
}

// ---------------- dense kernel 1: xwb[p][n][o] = bf16( xin[n,:] @ W_p ) ----------------
// v7: block = 128-node tile (grid 782). Stage the x-tile ONCE into LDS (reg-staged XOR
// swizzle, r4-verified conflict-free) and reuse it for all 17 planes: global x traffic
// drops 17x (218MB -> 12.8MB). Per plane: wave wid = och-quarter, 8 independent chunks
// {2 ds_read_b128 (2-way, free), 2 MFMA, pack, 8B store}; weights prefetched 1 plane
// ahead (r4-verified). Write-stream-bound by design (213MB).
__global__ __launch_bounds__(256, 4) void xw_gemm(const unsigned short* __restrict__ xin,
                                                  const unsigned short* __restrict__ wt,
                                                  unsigned short* __restrict__ xwb) {
    __shared__ __attribute__((aligned(16))) unsigned char Ash[128 * 128]; // 16 KB
    const int tid  = threadIdx.x;
    const int ob   = tid >> 6;
    const int lane = tid & 63;
    const int c = lane & 15;
    const int q = lane >> 4;
    const int n0 = blockIdx.x * 128;

    // ---- stage 128 x-rows (2 threads/row, 4x16B loads), XOR-swizzled slots ----
    {
        const int half = tid & 1;
        const int i = tid >> 1;               // row 0..127, one pass
        const unsigned short* xr = xin + (size_t)(n0 + i) * DD + half * 32;
        s16x8 v0 = *(const s16x8*)(xr);
        s16x8 v1 = *(const s16x8*)(xr + 8);
        s16x8 v2 = *(const s16x8*)(xr + 16);
        s16x8 v3 = *(const s16x8*)(xr + 24);
        unsigned char* bp = Ash + i * 128;
        const int h8 = (i & 7);
        *(s16x8*)(bp + (((half * 4 + 0) ^ h8) * 16)) = v0;
        *(s16x8*)(bp + (((half * 4 + 1) ^ h8) * 16)) = v1;
        *(s16x8*)(bp + (((half * 4 + 2) ^ h8) * 16)) = v2;
        *(s16x8*)(bp + (((half * 4 + 3) ^ h8) * 16)) = v3;
    }
    __syncthreads();

    // A-operand (weights, m=och): loaded once per plane, prefetched one plane ahead
    const unsigned short* wb0 = wt + (size_t)(ob * 16 + c) * DD + q * 8;
    s16x8 w0 = *(const s16x8*)(wb0);
    s16x8 w1 = *(const s16x8*)(wb0 + 32);

    for (int p = 0; p < 17; ++p) {
        const unsigned short* nw = wb0 + (size_t)(p < 16 ? p + 1 : 16) * (DD * DD);
        s16x8 nw0 = *(const s16x8*)(nw);
        s16x8 nw1 = *(const s16x8*)(nw + 32);

        unsigned short* orow = xwb + ((size_t)p * NNP + n0 + c) * DD + ob * 16 + q * 4;
        #pragma unroll
        for (int t = 0; t < 8; ++t) {
            const int rr = t * 16 + c;
            const unsigned char* ap = Ash + rr * 128;
            const int off = (q ^ (rr & 7)) * 16;
            s16x8 a0 = *(const s16x8*)(ap + off);
            s16x8 a1 = *(const s16x8*)(ap + (off ^ 64));
            f32x4 acc = {0.f, 0.f, 0.f, 0.f};
            acc = __builtin_amdgcn_mfma_f32_16x16x32_bf16(w0, a0, acc, 0, 0, 0);
            acc = __builtin_amdgcn_mfma_f32_16x16x32_bf16(w1, a1, acc, 0, 0, 0);
            uint2 val;
            val.x = pack2(acc[0], acc[1]);
            val.y = pack2(acc[2], acc[3]);
            *(uint2*)(orow + (size_t)t * 16 * DD) = val;
        }
        w0 = nw0; w1 = nw1;
    }
}

// ---------------- dense kernel 2: per-node gather-aggregate ----------------
__global__ __launch_bounds__(256, 8) void aggregate(
    const unsigned short* __restrict__ xwb,  // [17][NNP][64] bf16
    const int* __restrict__ rp,              // [NN+1] CSR by dst
    const unsigned int* __restrict__ ep,     // [E] src | et<<20
    const float* __restrict__ bias,
    const float* __restrict__ xres,          // fp32 residual or nullptr
    unsigned short* __restrict__ outb,       // bf16 out (layer 1) or nullptr
    float* __restrict__ outf)                // fp32 out (layer 2) or nullptr
{
    const int tid  = threadIdx.x;
    const int wid  = tid >> 6;
    const int lane = tid & 63;
    const int n = blockIdx.x * 4 + wid;
    if (n >= NN) return;

    const int s0 = rp[n];
    const int s1 = rp[n + 1];

    float acc0 = bf2f(xwb[((size_t)16 * NNP + n) * DD + lane]);   // self transform
    acc0 += bias[lane];
    if (xres) acc0 += xres[(size_t)n * DD + lane];
    float acc1 = 0.f, acc2 = 0.f, acc3 = 0.f;

    for (int base = s0; base < s1; base += 16) {
        const int m = s1 - base;
        unsigned wv[16];
        #pragma unroll
        for (int k = 0; k < 16; ++k)
            wv[k] = ep[min(base + k, s1 - 1)];
        float vals[16];
        #pragma unroll
        for (int k = 0; k < 16; ++k) {
            const unsigned w = wv[k];
            vals[k] = bf2f(xwb[((size_t)(w >> 20) * NNP + (w & 0xFFFFFu)) * DD + lane]);
        }
        #pragma unroll
        for (int k = 0; k < 16; ++k) {
            float v = (k < m) ? vals[k] : 0.f;
            if ((k & 3) == 0) acc0 += v;
            else if ((k & 3) == 1) acc1 += v;
            else if ((k & 3) == 2) acc2 += v;
            else acc3 += v;
        }
    }

    float acc = (acc0 + acc1) + (acc2 + acc3);
    acc = fmaxf(acc, 0.f);
    if (outb) outb[(size_t)n * DD + lane] = f2bf(acc);
    if (outf) outf[(size_t)n * DD + lane] = acc;
}

// ---------------- fallback fused layer (r4, verified 152us/layer) ----------------
__global__ __launch_bounds__(256, 4) void fused_layer(
    const unsigned short* __restrict__ xb,
    const unsigned short* __restrict__ wt,
    const int* __restrict__ rp,
    const unsigned int* __restrict__ ep,
    const float* __restrict__ bias,
    const float* __restrict__ xres,
    unsigned short* __restrict__ outb,
    float* __restrict__ outf)
{
    __shared__ __attribute__((aligned(16))) unsigned char Ash[CAPROWS * 128];
    __shared__ __attribute__((aligned(8)))  unsigned char dlb[DLCAP + 32];

    const int tid  = threadIdx.x;
    const int wid  = tid >> 6;
    const int lane = tid & 63;
    const int c = lane & 15;
    const int q = lane >> 4;
    const int tile = blockIdx.x;
    const int n0 = tile * 16;

    int rpv = 0;
    if (lane < 17) rpv = rp[tile * 16 + lane];
    const int e0  = __shfl(rpv, 0, 64);
    const int cnt = __shfl(rpv, 16, 64) - e0;

    {
        const int lim = cnt < DLCAP ? cnt : DLCAP;
        for (int i = tid; i < lim; i += 256)
            dlb[i] = (unsigned char)(ep[e0 + i] >> 20);
        if (tid < 32) {
            int p = lim + tid;
            if (p < DLCAP + 32) dlb[p] = 0xFF;
        }
    }
    {
        const int nrows = cnt < CAPROWS ? cnt : CAPROWS;
        const int half = tid & 1;
        for (int i = tid >> 1; i < nrows; i += 128) {
            int src = (int)(ep[e0 + i] & 0xFFFFF);
            const unsigned short* xr = xb + (size_t)src * DD + half * 32;
            s16x8 v0 = *(const s16x8*)(xr);
            s16x8 v1 = *(const s16x8*)(xr + 8);
            s16x8 v2 = *(const s16x8*)(xr + 16);
            s16x8 v3 = *(const s16x8*)(xr + 24);
            unsigned char* bp = Ash + i * 128;
            const int h8 = (i & 7);
            *(s16x8*)(bp + (((half * 4 + 0) ^ h8) * 16)) = v0;
            *(s16x8*)(bp + (((half * 4 + 1) ^ h8) * 16)) = v1;
            *(s16x8*)(bp + (((half * 4 + 2) ^ h8) * 16)) = v2;
            *(s16x8*)(bp + (((half * 4 + 3) ^ h8) * 16)) = v3;
        }
    }
    __syncthreads();

    const bool dlOK = (cnt <= DLCAP);
    const int och = wid * 16 + c;
    const unsigned short* wbase = wt + (size_t)och * DD + q * 8;
    const short one = (short)0x3F80;

    auto plane_body = [&](int r, s16x8 W0, s16x8 W1, f32x4& Dst) {
        const int s0 = __shfl(rpv, r, 64);
        const int s1 = __shfl(rpv, r + 1, 64);
        for (int b0 = s0; b0 < s1; b0 += 16) {
            const int rem = s1 - b0;
            const int lbase = b0 - e0;
            unsigned da;
            if (dlOK) {
                const unsigned* dl32 = (const unsigned*)dlb;
                int idx = lbase + q * 4;
                int w = idx >> 2;
                int sh = (idx & 3) * 8;
                unsigned long long pa =
                    ((unsigned long long)dl32[w + 1] << 32) | dl32[w];
                da = (unsigned)(pa >> sh);
            } else {
                int eA = min(b0 + c, s1 - 1);
                unsigned wa = ep[eA];
                int dl = (b0 + c < s1) ? (int)(wa >> 20) : 31;
                unsigned x0 = (unsigned)__shfl(dl, q * 4 + 0, 64) & 255u;
                unsigned x1 = (unsigned)__shfl(dl, q * 4 + 1, 64) & 255u;
                unsigned x2 = (unsigned)__shfl(dl, q * 4 + 2, 64) & 255u;
                unsigned x3 = (unsigned)__shfl(dl, q * 4 + 3, 64) & 255u;
                da = x0 | (x1 << 8) | (x2 << 16) | (x3 << 24);
            }
            s16x8 a2;
            #pragma unroll
            for (int j = 0; j < 4; ++j) {
                int jj = q * 4 + j;
                a2[j] = ((int)((da >> (8 * j)) & 255) == c && jj < rem) ? one : (short)0;
                a2[j + 4] = 0;
            }
            int rA = min(b0 + c, s1 - 1) - e0;
            s16x8 a0, a1;
            if (rA < CAPROWS) {
                const unsigned char* ap = Ash + rA * 128;
                const int off = (q ^ (rA & 7)) * 16;
                a0 = *(const s16x8*)(ap + off);
                a1 = *(const s16x8*)(ap + (off ^ 64));
            } else {
                int src = (int)(ep[e0 + rA] & 0xFFFFF);
                const unsigned short* xr = xb + (size_t)src * DD + q * 8;
                a0 = *(const s16x8*)(xr);
                a1 = *(const s16x8*)(xr + 32);
            }
            f32x4 cA = {0.f, 0.f, 0.f, 0.f};
            cA = __builtin_amdgcn_mfma_f32_16x16x32_bf16(a0, W0, cA, 0, 0, 0);
            cA = __builtin_amdgcn_mfma_f32_16x16x32_bf16(a1, W1, cA, 0, 0, 0);
            s16x8 bv;
            #pragma unroll
            for (int j = 0; j < 4; ++j) {
                bv[j]     = (short)f2bf(cA[j]);
                bv[j + 4] = 0;
            }
            Dst = __builtin_amdgcn_mfma_f32_16x16x32_bf16(a2, bv, Dst, 0, 0, 0);
        }
    };

    s16x8 wc0 = *(const s16x8*)(wbase);
    s16x8 wc1 = *(const s16x8*)(wbase + 32);
    f32x4 D0 = {0.f, 0.f, 0.f, 0.f};
    f32x4 D1 = {0.f, 0.f, 0.f, 0.f};

    for (int rr = 0; rr < 8; ++rr) {
        const int r = rr * 2;
        const unsigned short* p1 = wbase + (size_t)(r + 1) * (DD * DD);
        s16x8 wn0 = *(const s16x8*)(p1);
        s16x8 wn1 = *(const s16x8*)(p1 + 32);
        plane_body(r, wc0, wc1, D0);
        const int r2 = (r + 2 <= 16) ? r + 2 : 16;
        const unsigned short* p2 = wbase + (size_t)r2 * (DD * DD);
        s16x8 t0 = *(const s16x8*)(p2);
        s16x8 t1 = *(const s16x8*)(p2 + 32);
        plane_body(r + 1, wn0, wn1, D1);
        wc0 = t0; wc1 = t1;
    }
    {
        const unsigned short* xr = xb + (size_t)(n0 + c) * DD + q * 8;
        s16x8 a0 = *(const s16x8*)(xr);
        s16x8 a1 = *(const s16x8*)(xr + 32);
        D0 = __builtin_amdgcn_mfma_f32_16x16x32_bf16(a0, wc0, D0, 0, 0, 0);
        D1 = __builtin_amdgcn_mfma_f32_16x16x32_bf16(a1, wc1, D1, 0, 0, 0);
    }
    f32x4 Dacc = D0 + D1;

    const float bc = bias[och];
    #pragma unroll
    for (int v = 0; v < 4; ++v) {
        const int node = n0 + q * 4 + v;
        float val = Dacc[v] + bc;
        if (xres) val += xres[(size_t)node * DD + och];
        val = fmaxf(val, 0.f);
        if (outf) outf[(size_t)node * DD + och] = val;
        if (outb) {
            float nb = __shfl_xor(val, 1, 64);
            if (!(c & 1))
                *(unsigned int*)(outb + (size_t)node * DD + och) = pack2(val, nb);
        }
    }
}

// ================= launch =================

extern "C" void kernel_launch(void* const* d_in, const int* in_sizes, int n_in,
                              void* d_out, int out_size, void* d_ws, size_t ws_size,
                              hipStream_t stream)
{
    (void)in_sizes; (void)n_in; (void)out_size;
    const float* x    = (const float*)d_in[0];
    const int*   ei   = (const int*)d_in[1];
    const int*   et   = (const int*)d_in[2];
    const float* W1   = (const float*)d_in[3];
    const float* sw1  = (const float*)d_in[4];
    const float* b1   = (const float*)d_in[5];
    const float* W2   = (const float*)d_in[6];
    const float* sw2  = (const float*)d_in[7];
    const float* b2   = (const float*)d_in[8];
    float* out = (float*)d_out;

    const int* srcA = ei;
    const int* dstA = ei + NE;

    char* ws = (char*)d_ws;
    unsigned short* xb   = (unsigned short*)(ws);                 // 12,800,000
    unsigned short* h1b  = (unsigned short*)(ws + 12800000);      // 12,800,000
    unsigned short* wt2  = (unsigned short*)(ws + 25600000);      //    278,528
    unsigned int*   ep   = (unsigned int*)(ws + 25878528);        //  5,000,000
    int*            rp   = (int*)(ws + 30878528);                 //    400,004 (ends 31,278,532)
    // cnt/cur/part are DEAD once xw_gemm runs -> xwb aliases them (saves 800KB of REQ)
    const size_t XWB_OFF = 31278592;                              // 128-aligned
    int*            cnt  = (int*)(ws + XWB_OFF);                  //    400,000
    int*            cur  = (int*)(ws + XWB_OFF + 400000);         //    400,000
    int*            part = (int*)(ws + XWB_OFF + 800000);         //      1,600
    unsigned short* xwb  = (unsigned short*)(ws + XWB_OFF);       // 217,808,896 (17*NNP*64*2)
    const size_t REQ = XWB_OFF + (size_t)17 * NNP * DD * 2;       // 249,087,488

    const int NB_E    = (NE + 255) / 256;        // 4883
    const int NB_ELEM = (NN * DD + 255) / 256;   // 25000
    const int WPL = 17 * DD * DD;                // wt2 per-layer stride

    const bool dense = (ws_size >= REQ);

    hipMemsetAsync(cnt, 0, NBINS * sizeof(int), stream);
    if (dense) {
        // merged hist_dst + prep_w + prep_x
        prologue<<<NB_E_C + NB_W_C + NB_X_C, 256, 0, stream>>>(
            dstA, W1, sw1, W2, sw2, x, cnt, wt2, xb);
        scan1<<<NBLK_SCAN, 256, 0, stream>>>(cnt, rp, part);
        scan2<<<1, 512, 0, stream>>>(part, rp);
        scan3<<<NBLK_SCAN, 256, 0, stream>>>(rp, part, cur);
        scatter_dst<<<NB_E, 256, 0, stream>>>(srcA, dstA, et, cur, ep);

        const int NB_G = NNP / 128;          // 782
        const int NB_A = (NN + 3) / 4;       // 25000
        // layer 1
        xw_gemm<<<NB_G, 256, 0, stream>>>(xb, wt2, xwb);
        aggregate<<<NB_A, 256, 0, stream>>>(xwb, rp, ep, b1, x, h1b, nullptr);
        // layer 2
        xw_gemm<<<NB_G, 256, 0, stream>>>(h1b, wt2 + WPL, xwb);
        aggregate<<<NB_A, 256, 0, stream>>>(xwb, rp, ep, b2, nullptr, nullptr, out);
    } else {
        hist_key<<<NB_E, 256, 0, stream>>>(dstA, et, cnt);
        scan1<<<NBLK_SCAN, 256, 0, stream>>>(cnt, rp, part);
        scan2<<<1, 512, 0, stream>>>(part, rp);
        scan3<<<NBLK_SCAN, 256, 0, stream>>>(rp, part, cur);
        scatter_key<<<NB_E, 256, 0, stream>>>(srcA, dstA, et, cur, ep);
        prep_w2<<<(2 * 17 * DD * DD + 255) / 256, 256, 0, stream>>>(W1, sw1, W2, sw2, wt2);
        prep_x2<<<NB_ELEM, 256, 0, stream>>>(x, xb);
        fused_layer<<<NTILE, 256, 0, stream>>>(xb, wt2, rp, ep, b1, x, h1b, nullptr);
        fused_layer<<<NTILE, 256, 0, stream>>>(h1b, wt2 + WPL, rp, ep, b2, nullptr, nullptr, out);
    }
}